// Round 1
// baseline (104.215 us; speedup 1.0000x reference)
//
#include <hip/hip_runtime.h>

// PointCloudGrouper: ball query (first NSAMPLE=512 in index order within r=0.25)
// + gather + re-center.  xyz [B=128, N=8192, 3] f32, centers [1, 27, 3] f32,
// out [B*27, 512, 3] f32.
//
// One 256-thread block per (b, p) pair.  Chunked scan: 256 points per chunk,
// wave ballot + popc prefix + 4-wave LDS scan assigns output slots in index
// order.  Running slot count `base` is block-uniform -> kept in a register.
// Distance test done in f64 so the mask decision matches a float64 numpy
// reference exactly (f32 knife-edge flips would blow absmax).

constexpr int P   = 27;
constexpr int N   = 8192;
constexpr int S   = 512;   // NSAMPLE
constexpr int BLK = 256;

__global__ __launch_bounds__(BLK) void pc_group_kernel(
    const float* __restrict__ xyz, const float* __restrict__ centers,
    float* __restrict__ out) {
  // XCD-aware swizzle: blocks dispatch round-robin over 8 XCDs (heuristic).
  // Put all 27 centers of a batch (and consecutive batches) on one XCD so the
  // 27x re-read of the 768 KB batch slab stays in that XCD's 4 MB L2.
  int i = blockIdx.x;                // [0, 3456)
  int xcd = i & 7;
  int j = i >> 3;                    // [0, 432) = 16 batches * 27 centers
  int b = xcd * 16 + j / P;
  int p = j - (j / P) * P;

  const float* pts = xyz + (size_t)b * (N * 3);
  float cx = centers[p * 3 + 0];
  float cy = centers[p * 3 + 1];
  float cz = centers[p * 3 + 2];
  double cxd = (double)cx, cyd = (double)cy, czd = (double)cz;

  float* o = out + ((size_t)b * P + p) * (S * 3);

  __shared__ int   s_wavesum[BLK / 64];
  __shared__ float s_first[3];

  int tid  = threadIdx.x;
  int wave = tid >> 6;
  int lane = tid & 63;

  int base = 0;  // block-uniform running count of filled slots
  for (int start = 0; start < N; start += BLK) {
    int n = start + tid;
    // 12 contiguous bytes per lane -> coalesced (dwordx3-class) load
    float x = pts[n * 3 + 0];
    float y = pts[n * 3 + 1];
    float z = pts[n * 3 + 2];
    double dx = (double)x - cxd;
    double dy = (double)y - cyd;
    double dz = (double)z - czd;
    double d2 = dx * dx + dy * dy + dz * dz;
    bool inball = d2 < 0.0625;  // r^2 = 0.25^2, exact in binary

    unsigned long long m = __ballot(inball);
    if (lane == 0) s_wavesum[wave] = __popcll(m);
    __syncthreads();

    int woff = 0, total = 0;
#pragma unroll
    for (int w = 0; w < BLK / 64; ++w) {
      int c = s_wavesum[w];
      total += c;
      if (w < wave) woff += c;
    }
    int pre  = __popcll(m & ((1ull << lane) - 1ull));
    int slot = base + woff + pre;
    if (inball && slot < S) {
      float fx = x - cx, fy = y - cy, fz = z - cz;
      o[slot * 3 + 0] = fx;
      o[slot * 3 + 1] = fy;
      o[slot * 3 + 2] = fz;
      if (slot == 0) {  // first found point: pad value for the tail
        s_first[0] = fx; s_first[1] = fy; s_first[2] = fz;
      }
    }
    base += total;
    __syncthreads();          // s_first/s_wavesum ready; protects next overwrite
    if (base >= S) break;     // uniform branch
  }

  // Pad slots [base, S) with first found point (index 0 if none found).
  float fx, fy, fz;
  if (base > 0) {
    fx = s_first[0]; fy = s_first[1]; fz = s_first[2];
  } else {
    fx = pts[0] - cx; fy = pts[1] - cy; fz = pts[2] - cz;
  }
  int cnt = base < S ? base : S;
  for (int slot = cnt + tid; slot < S; slot += BLK) {
    o[slot * 3 + 0] = fx;
    o[slot * 3 + 1] = fy;
    o[slot * 3 + 2] = fz;
  }
}

extern "C" void kernel_launch(void* const* d_in, const int* in_sizes, int n_in,
                              void* d_out, int out_size, void* d_ws, size_t ws_size,
                              hipStream_t stream) {
  const float* xyz     = (const float*)d_in[0];   // [128, 8192, 3]
  const float* centers = (const float*)d_in[1];   // [1, 27, 3]
  float* out           = (float*)d_out;           // [3456, 512, 3]
  constexpr int NBLOCKS = 128 * P;                // 3456
  pc_group_kernel<<<NBLOCKS, BLK, 0, stream>>>(xyz, centers, out);
}

// Round 2
// 75.329 us; speedup vs baseline: 1.3835x; 1.3835x over previous
//
#include <hip/hip_runtime.h>

// PointCloudGrouper: ball query (first NSAMPLE=512 in index order, r=0.25)
// + gather + re-center.  xyz [128, 8192, 3] f32, centers [1,27,3] f32,
// out [3456, 512, 3] f32.
//
// Two-phase: centers are a 3x3x3 grid at {-0.25,0,0.25}^3, radius 0.25.
// A point is in SOME ball iff dist to nearest grid point < r (per-axis
// round+clamp is the exact nearest for an axis-aligned grid). Only ~5% of
// N(0,1) points qualify. Phase 1 compacts candidates per batch (order
// preserved, conservative f32 filter +1e-4 slack). Phase 2 = per-(b,p)
// ordered ballot-scan over ~400 candidates with the exact f64 test.

constexpr int P   = 27;
constexpr int N   = 8192;
constexpr int S   = 512;
constexpr int B   = 128;
constexpr int BLK = 256;

// ---------------- Phase 1: per-batch ordered candidate compaction ----------
__global__ __launch_bounds__(1024) void pc_compact_kernel(
    const float* __restrict__ xyz, float4* __restrict__ cand,
    int* __restrict__ ccnt) {
  int b    = blockIdx.x;
  int tid  = threadIdx.x;
  int lane = tid & 63;
  int wave = tid >> 6;
  __shared__ int s_wsum[16];

  // thread t owns points [8t, 8t+8) -> 96 contiguous bytes = 6 float4
  const float4* p4 = (const float4*)(xyz + (size_t)b * (N * 3));
  float4 f[6];
#pragma unroll
  for (int k = 0; k < 6; ++k) f[k] = p4[tid * 6 + k];
  float xs[8], ys[8], zs[8];
  {
    const float* fp = (const float*)f;
#pragma unroll
    for (int k = 0; k < 8; ++k) {
      xs[k] = fp[3 * k + 0]; ys[k] = fp[3 * k + 1]; zs[k] = fp[3 * k + 2];
    }
  }

  unsigned mask = 0;
#pragma unroll
  for (int k = 0; k < 8; ++k) {
    // nearest grid center per axis: clamp(round(x/0.25), -1, 1) * 0.25
    float cx = fminf(fmaxf(roundf(xs[k] * 4.0f), -1.0f), 1.0f) * 0.25f;
    float cy = fminf(fmaxf(roundf(ys[k] * 4.0f), -1.0f), 1.0f) * 0.25f;
    float cz = fminf(fmaxf(roundf(zs[k] * 4.0f), -1.0f), 1.0f) * 0.25f;
    float dx = xs[k] - cx, dy = ys[k] - cy, dz = zs[k] - cz;
    float d2 = dx * dx + dy * dy + dz * dz;
    // conservative: never drop a point phase 2's exact f64 test would accept
    if (d2 < 0.0625f + 1e-4f) mask |= 1u << k;
  }

  int pcnt = __popc(mask);
  int incl = pcnt;  // inclusive prefix over the 64 lanes
#pragma unroll
  for (int d = 1; d < 64; d <<= 1) {
    int v = __shfl_up(incl, d);
    if (lane >= d) incl += v;
  }
  if (lane == 63) s_wsum[wave] = incl;
  __syncthreads();
  int woff = 0, total = 0;
#pragma unroll
  for (int w = 0; w < 16; ++w) {
    int c = s_wsum[w];
    if (w < wave) woff += c;
    total += c;
  }
  int pos = woff + (incl - pcnt);

  float4* cb = cand + (size_t)b * N;
#pragma unroll
  for (int k = 0; k < 8; ++k) {
    if (mask & (1u << k)) cb[pos++] = make_float4(xs[k], ys[k], zs[k], 0.0f);
  }
  if (tid == 0) ccnt[b] = total;
}

// ---------------- Phase 2: per-(b,p) ordered ball query over candidates ----
__global__ __launch_bounds__(BLK) void pc_group2_kernel(
    const float4* __restrict__ cand, const int* __restrict__ ccnt,
    const float* __restrict__ xyz, const float* __restrict__ centers,
    float* __restrict__ out) {
  // XCD swizzle: all 27 centers of a batch on one XCD (candidate list L2-hot)
  int i   = blockIdx.x;
  int xcd = i & 7;
  int j   = i >> 3;
  int b   = xcd * 16 + j / P;
  int p   = j - (j / P) * P;

  float cx = centers[p * 3 + 0];
  float cy = centers[p * 3 + 1];
  float cz = centers[p * 3 + 2];
  double cxd = (double)cx, cyd = (double)cy, czd = (double)cz;

  const float4* cb = cand + (size_t)b * N;
  int cnt = ccnt[b];
  float* o = out + ((size_t)b * P + p) * (S * 3);

  __shared__ int   s_wsum[BLK / 64];
  __shared__ float s_first[3];

  int tid  = threadIdx.x;
  int wave = tid >> 6;
  int lane = tid & 63;

  int base = 0;
  for (int start = 0; start < cnt; start += BLK) {
    int idx  = start + tid;
    bool act = idx < cnt;
    float4 pt = make_float4(0.0f, 0.0f, 0.0f, 0.0f);
    if (act) pt = cb[idx];
    double dx = (double)pt.x - cxd;
    double dy = (double)pt.y - cyd;
    double dz = (double)pt.z - czd;
    double d2 = dx * dx + dy * dy + dz * dz;
    bool inball = act && (d2 < 0.0625);

    unsigned long long m = __ballot(inball);
    if (lane == 0) s_wsum[wave] = __popcll(m);
    __syncthreads();

    int woff = 0, total = 0;
#pragma unroll
    for (int w = 0; w < BLK / 64; ++w) {
      int c = s_wsum[w];
      total += c;
      if (w < wave) woff += c;
    }
    int pre  = __popcll(m & ((1ull << lane) - 1ull));
    int slot = base + woff + pre;
    if (inball && slot < S) {
      float fx = pt.x - cx, fy = pt.y - cy, fz = pt.z - cz;
      o[slot * 3 + 0] = fx;
      o[slot * 3 + 1] = fy;
      o[slot * 3 + 2] = fz;
      if (slot == 0) { s_first[0] = fx; s_first[1] = fy; s_first[2] = fz; }
    }
    base += total;
    __syncthreads();
    if (base >= S) break;
  }

  // Pad [base, S) with first found point (point index 0 if none found).
  float fx, fy, fz;
  if (base > 0) {
    fx = s_first[0]; fy = s_first[1]; fz = s_first[2];
  } else {
    const float* pts = xyz + (size_t)b * (N * 3);
    fx = pts[0] - cx; fy = pts[1] - cy; fz = pts[2] - cz;
  }
  int filled = base < S ? base : S;
  for (int slot = filled + tid; slot < S; slot += BLK) {
    o[slot * 3 + 0] = fx;
    o[slot * 3 + 1] = fy;
    o[slot * 3 + 2] = fz;
  }
}

// ---------------- Fallback: R0 single-phase kernel (if ws too small) -------
__global__ __launch_bounds__(BLK) void pc_group_kernel(
    const float* __restrict__ xyz, const float* __restrict__ centers,
    float* __restrict__ out) {
  int i = blockIdx.x;
  int xcd = i & 7;
  int j = i >> 3;
  int b = xcd * 16 + j / P;
  int p = j - (j / P) * P;

  const float* pts = xyz + (size_t)b * (N * 3);
  float cx = centers[p * 3 + 0];
  float cy = centers[p * 3 + 1];
  float cz = centers[p * 3 + 2];
  double cxd = (double)cx, cyd = (double)cy, czd = (double)cz;
  float* o = out + ((size_t)b * P + p) * (S * 3);

  __shared__ int   s_wavesum[BLK / 64];
  __shared__ float s_first[3];
  int tid = threadIdx.x, wave = tid >> 6, lane = tid & 63;

  int base = 0;
  for (int start = 0; start < N; start += BLK) {
    int n = start + tid;
    float x = pts[n * 3 + 0], y = pts[n * 3 + 1], z = pts[n * 3 + 2];
    double dx = (double)x - cxd, dy = (double)y - cyd, dz = (double)z - czd;
    bool inball = dx * dx + dy * dy + dz * dz < 0.0625;

    unsigned long long m = __ballot(inball);
    if (lane == 0) s_wavesum[wave] = __popcll(m);
    __syncthreads();
    int woff = 0, total = 0;
#pragma unroll
    for (int w = 0; w < BLK / 64; ++w) {
      int c = s_wavesum[w];
      total += c;
      if (w < wave) woff += c;
    }
    int pre = __popcll(m & ((1ull << lane) - 1ull));
    int slot = base + woff + pre;
    if (inball && slot < S) {
      float fx = x - cx, fy = y - cy, fz = z - cz;
      o[slot * 3 + 0] = fx; o[slot * 3 + 1] = fy; o[slot * 3 + 2] = fz;
      if (slot == 0) { s_first[0] = fx; s_first[1] = fy; s_first[2] = fz; }
    }
    base += total;
    __syncthreads();
    if (base >= S) break;
  }
  float fx, fy, fz;
  if (base > 0) { fx = s_first[0]; fy = s_first[1]; fz = s_first[2]; }
  else { fx = pts[0] - cx; fy = pts[1] - cy; fz = pts[2] - cz; }
  int filled = base < S ? base : S;
  for (int slot = filled + tid; slot < S; slot += BLK) {
    o[slot * 3 + 0] = fx; o[slot * 3 + 1] = fy; o[slot * 3 + 2] = fz;
  }
}

extern "C" void kernel_launch(void* const* d_in, const int* in_sizes, int n_in,
                              void* d_out, int out_size, void* d_ws, size_t ws_size,
                              hipStream_t stream) {
  const float* xyz     = (const float*)d_in[0];   // [128, 8192, 3]
  const float* centers = (const float*)d_in[1];   // [1, 27, 3]
  float* out           = (float*)d_out;           // [3456, 512, 3]

  const size_t cand_bytes = (size_t)B * N * sizeof(float4);  // 16.78 MB
  const size_t need       = cand_bytes + B * sizeof(int);

  if (ws_size >= need) {
    float4* cand = (float4*)d_ws;
    int*    ccnt = (int*)((char*)d_ws + cand_bytes);
    pc_compact_kernel<<<B, 1024, 0, stream>>>(xyz, cand, ccnt);
    pc_group2_kernel<<<B * P, BLK, 0, stream>>>(cand, ccnt, xyz, centers, out);
  } else {
    pc_group_kernel<<<B * P, BLK, 0, stream>>>(xyz, centers, out);
  }
}